// Round 2
// baseline (710.166 us; speedup 1.0000x reference)
//
#include <hip/hip_runtime.h>
#include <math.h>

typedef __attribute__((ext_vector_type(8))) __bf16 bf16x8;
typedef __attribute__((ext_vector_type(4))) float f32x4;
typedef unsigned short ushort_t;
typedef unsigned int uint_t;

#define MFMA16(a,b,c) __builtin_amdgcn_mfma_f32_16x16x32_bf16(a,b,c,0,0,0)

#define GLD16(gp, lp) __builtin_amdgcn_global_load_lds( \
  (__attribute__((address_space(1))) const void*)(gp), \
  (__attribute__((address_space(3))) void*)(lp), 16, 0, 0)

__device__ __forceinline__ ushort_t f2bf(float f) {
  uint_t u = __builtin_bit_cast(uint_t, f);
  u = (u + 0x7fffu + ((u >> 16) & 1u)) >> 16;
  return (ushort_t)u;
}

// ---------------- fp32 -> bf16 elementwise convert ----------------
__global__ __launch_bounds__(256) void convf(const float* __restrict__ in,
                                             ushort_t* __restrict__ out, int n4) {
  int i = blockIdx.x * 256 + threadIdx.x;
  if (i < n4) {
    float4 v = ((const float4*)in)[i];
    ushort4 o;
    o.x = f2bf(v.x); o.y = f2bf(v.y); o.z = f2bf(v.z); o.w = f2bf(v.w);
    ((ushort4*)out)[i] = o;
  }
}

// ---------------- GEMM: C[m][n] = sum_k A[m][k]*B[n][k] + bias[n] ----------------
// A: [M][K] bf16, B: [N][K] bf16 (i.e. x @ W.T with W stored [out,in])
// OUT_MODE 0: fp32 row-major [M][N]
// OUT_MODE 1: bf16 row-major [M][N]
// OUT_MODE 2: fp32 head-major [N/64][M][64]   (for key_/value outputs)
template<int OUT_MODE>
__global__ __launch_bounds__(256)
void gemm_bt(const ushort_t* __restrict__ A, const ushort_t* __restrict__ B,
             const float* __restrict__ bias, void* __restrict__ Cout,
             int M, int N, int K)
{
  __shared__ __align__(16) ushort_t Al[128 * 32];
  __shared__ __align__(16) ushort_t Bl[128 * 32];
  const int tid = threadIdx.x;
  const int w = tid >> 6, l = tid & 63;
  const int lr = l & 15, lg = l >> 4;
  const int bm = blockIdx.x * 128, bn = blockIdx.y * 128;
  const int wr = w >> 1, wc = w & 1;
  f32x4 acc[4][4] = {};

  const int crow = l >> 2;         // row within 16-row staging chunk
  const int ccol = (l & 3) * 8;    // element col within 32

  for (int k0 = 0; k0 < K; k0 += 32) {
    __syncthreads();
#pragma unroll
    for (int i = 0; i < 2; ++i) {
      const int c = w * 2 + i;     // 8 chunks of 16 rows
      GLD16(A + (size_t)(bm + c * 16 + crow) * K + k0 + ccol, &Al[c * 512]);
      GLD16(B + (size_t)(bn + c * 16 + crow) * K + k0 + ccol, &Bl[c * 512]);
    }
    __syncthreads();
    bf16x8 af[4], bfr[4];
#pragma unroll
    for (int mi = 0; mi < 4; ++mi)
      af[mi] = *(const bf16x8*)&Al[(wr * 64 + mi * 16 + lr) * 32 + lg * 8];
#pragma unroll
    for (int ni = 0; ni < 4; ++ni)
      bfr[ni] = *(const bf16x8*)&Bl[(wc * 64 + ni * 16 + lr) * 32 + lg * 8];
#pragma unroll
    for (int mi = 0; mi < 4; ++mi)
#pragma unroll
      for (int ni = 0; ni < 4; ++ni)
        acc[mi][ni] = MFMA16(af[mi], bfr[ni], acc[mi][ni]);
  }

#pragma unroll
  for (int mi = 0; mi < 4; ++mi) {
#pragma unroll
    for (int ni = 0; ni < 4; ++ni) {
      const int r0 = bm + wr * 64 + mi * 16 + lg * 4;
      const int cc = bn + wc * 64 + ni * 16 + lr;
      const float bv = bias ? bias[cc] : 0.0f;
#pragma unroll
      for (int jj = 0; jj < 4; ++jj) {
        float v = acc[mi][ni][jj] + bv;
        if (OUT_MODE == 0) {
          ((float*)Cout)[(size_t)(r0 + jj) * N + cc] = v;
        } else if (OUT_MODE == 1) {
          ((ushort_t*)Cout)[(size_t)(r0 + jj) * N + cc] = f2bf(v);
        } else {
          ((float*)Cout)[((size_t)(cc >> 6) * M + (r0 + jj)) * 64 + (cc & 63)] = v;
        }
      }
    }
  }
}

// ---------------- pack K: head-major fp32 -> bf16 [S][1024] ----------------
__global__ __launch_bounds__(256) void pack_kb(const float* __restrict__ Khead,
                                               ushort_t* __restrict__ Kb) {
  const int S = 4096;
  size_t i = (size_t)blockIdx.x * 256 + threadIdx.x;  // over 4M, = s*1024 + c
  int s = (int)(i >> 10), c = (int)(i & 1023);
  int h = c >> 6, dk = c & 63;
  Kb[i] = f2bf(Khead[((size_t)h * S + s) * 64 + dk]);
}

// ---------------- transpose V: head-major fp32 [16][S][64] -> bf16 [1024][S] ----------------
__global__ __launch_bounds__(256) void transpose_v(const float* __restrict__ Vhead,
                                                   ushort_t* __restrict__ Vt) {
  const int S = 4096;
  __shared__ ushort_t t[64][72];
  int b = blockIdx.x;               // 16 heads * 64 s-tiles
  int h = b >> 6, st = (b & 63) * 64;
  int tid = threadIdx.x;
  int c = tid & 63, r4 = tid >> 6;  // c: inner idx, r4: 0..3
#pragma unroll
  for (int i = 0; i < 16; ++i) {
    int row = r4 + i * 4;           // s offset 0..63
    t[row][c] = f2bf(Vhead[((size_t)h * S + st + row) * 64 + c]);
  }
  __syncthreads();
#pragma unroll
  for (int i = 0; i < 16; ++i) {
    int dk = r4 + i * 4;
    Vt[(size_t)(h * 64 + dk) * S + st + c] = t[c][dk];
  }
}

// ---------------- flash attention: causal, 16 heads, DK=64 ----------------
// Qb: bf16 [S][1024], Kb: bf16 [S][1024], Vt: bf16 [1024][S], Ao: bf16 [S][1024]
__global__ __launch_bounds__(256)
void attn(const ushort_t* __restrict__ Qb, const ushort_t* __restrict__ Kb,
          const ushort_t* __restrict__ Vt, ushort_t* __restrict__ Ao) {
  const int S = 4096, DM = 1024;
  const int h = blockIdx.y;
  const int q0 = blockIdx.x * 64;
  const int tid = threadIdx.x, w = tid >> 6, l = tid & 63;
  const int lr = l & 15, lg = l >> 4;
  const int qw = q0 + w * 16;       // this wave's 16 q rows
  __shared__ __align__(16) ushort_t plds[4][16 * 32];

  bf16x8 qf[2];
#pragma unroll
  for (int t = 0; t < 2; ++t)
    qf[t] = *(const bf16x8*)&Qb[(size_t)(qw + lr) * DM + h * 64 + t * 32 + lg * 8];

  f32x4 o[4] = {};
  float m[4], lsum[4];
#pragma unroll
  for (int jj = 0; jj < 4; ++jj) { m[jj] = -__builtin_inff(); lsum[jj] = 0.0f; }

  const int nsteps = (qw + 15) / 32 + 1;
  for (int st = 0; st < nsteps; ++st) {
    const int kt = st * 32;
    // K fragments: [key half][dk half]
    bf16x8 kf[2][2];
#pragma unroll
    for (int kh = 0; kh < 2; ++kh)
#pragma unroll
      for (int d = 0; d < 2; ++d)
        kf[kh][d] = *(const bf16x8*)&Kb[(size_t)(kt + kh * 16 + lr) * DM + h * 64 + d * 32 + lg * 8];

    f32x4 s0 = {}, s1 = {};
    s0 = MFMA16(qf[0], kf[0][0], s0);
    s0 = MFMA16(qf[1], kf[0][1], s0);
    s1 = MFMA16(qf[0], kf[1][0], s1);
    s1 = MFMA16(qf[1], kf[1][1], s1);

    const bool needmask = (kt + 31 > qw);
    float pm[4];
#pragma unroll
    for (int jj = 0; jj < 4; ++jj) {
      s0[jj] *= 0.125f;
      s1[jj] *= 0.125f;
      if (needmask) {
        int qrow = qw + lg * 4 + jj;
        if (kt + lr > qrow)      s0[jj] = -__builtin_inff();
        if (kt + 16 + lr > qrow) s1[jj] = -__builtin_inff();
      }
      pm[jj] = fmaxf(s0[jj], s1[jj]);
    }
#pragma unroll
    for (int d = 1; d < 16; d <<= 1)
#pragma unroll
      for (int jj = 0; jj < 4; ++jj)
        pm[jj] = fmaxf(pm[jj], __shfl_xor(pm[jj], d));

    float ps[4];
#pragma unroll
    for (int jj = 0; jj < 4; ++jj) {
      float mn = fmaxf(m[jj], pm[jj]);
      float al = __expf(m[jj] - mn);
      m[jj] = mn;
      s0[jj] = __expf(s0[jj] - mn);
      s1[jj] = __expf(s1[jj] - mn);
      ps[jj] = s0[jj] + s1[jj];
      lsum[jj] *= al;
#pragma unroll
      for (int t = 0; t < 4; ++t) o[t][jj] *= al;
    }
#pragma unroll
    for (int d = 1; d < 16; d <<= 1)
#pragma unroll
      for (int jj = 0; jj < 4; ++jj)
        ps[jj] += __shfl_xor(ps[jj], d);
#pragma unroll
    for (int jj = 0; jj < 4; ++jj) lsum[jj] += ps[jj];

    // write P tile (16x32) bf16 to this wave's LDS, reread as A-fragment
    ushort_t* pw = plds[w];
#pragma unroll
    for (int jj = 0; jj < 4; ++jj) {
      int r = lg * 4 + jj;
      pw[r * 32 + lr] = f2bf(s0[jj]);
      pw[r * 32 + 16 + lr] = f2bf(s1[jj]);
    }
    bf16x8 pa = *(const bf16x8*)&pw[lr * 32 + lg * 8];

#pragma unroll
    for (int t = 0; t < 4; ++t) {
      bf16x8 vf = *(const bf16x8*)&Vt[(size_t)(h * 64 + t * 16 + lr) * S + kt + lg * 8];
      o[t] = MFMA16(pa, vf, o[t]);
    }
  }

#pragma unroll
  for (int t = 0; t < 4; ++t)
#pragma unroll
    for (int jj = 0; jj < 4; ++jj) {
      float v = o[t][jj] / lsum[jj];
      Ao[(size_t)(qw + lg * 4 + jj) * DM + h * 64 + t * 16 + lr] = f2bf(v);
    }
}

// ---------------- launch ----------------
extern "C" void kernel_launch(void* const* d_in, const int* in_sizes, int n_in,
                              void* d_out, int out_size, void* d_ws, size_t ws_size,
                              hipStream_t stream) {
  const int S = 4096, DM = 1024;
  const size_t NE = (size_t)S * DM;        // 4M elements
  const size_t WE = (size_t)DM * DM;       // 1M elements

  const float* q  = (const float*)d_in[0];
  const float* k  = (const float*)d_in[1];
  const float* v  = (const float*)d_in[2];
  const float* Wq = (const float*)d_in[3];
  const float* bq = (const float*)d_in[4];
  const float* Wk = (const float*)d_in[5];
  const float* bk = (const float*)d_in[6];
  const float* Wv = (const float*)d_in[7];
  const float* bv = (const float*)d_in[8];
  const float* Wo = (const float*)d_in[9];
  const float* bo = (const float*)d_in[10];

  // workspace layout (40 MB high-water, overlays on dead buffers):
  //  [0,8M)    qb   (dead after gemm Q)  -> reused as kpb
  //  [8M,16M)  kb   (dead after gemm K)  -> reused as vt
  //  [16M,24M) vb   (dead after gemm V)  -> reused as ao
  //  [24M,32M) wqb/wkb/wvb/wob
  //  [32M,40M) qpb
  unsigned char* ws = (unsigned char*)d_ws;
  ushort_t* qb  = (ushort_t*)(ws);
  ushort_t* kb  = (ushort_t*)(ws + (8u << 20));
  ushort_t* vb  = (ushort_t*)(ws + (16u << 20));
  ushort_t* wqb = (ushort_t*)(ws + (24u << 20));
  ushort_t* wkb = (ushort_t*)(ws + (26u << 20));
  ushort_t* wvb = (ushort_t*)(ws + (28u << 20));
  ushort_t* wob = (ushort_t*)(ws + (30u << 20));
  ushort_t* qpb = (ushort_t*)(ws + (32u << 20));
  ushort_t* kpb = qb;   // overlay: qb dead after Q projection
  ushort_t* vt  = kb;   // overlay: kb dead after K projection
  ushort_t* ao  = vb;   // overlay: vb dead after V projection

  float* outO = (float*)d_out;
  float* keyO = outO + NE;
  float* valO = keyO + NE;

  // fp32 -> bf16 conversions
  convf<<<(int)(NE / 4 / 256), 256, 0, stream>>>(q, qb, (int)(NE / 4));
  convf<<<(int)(NE / 4 / 256), 256, 0, stream>>>(k, kb, (int)(NE / 4));
  convf<<<(int)(NE / 4 / 256), 256, 0, stream>>>(v, vb, (int)(NE / 4));
  convf<<<(int)(WE / 4 / 256), 256, 0, stream>>>(Wq, wqb, (int)(WE / 4));
  convf<<<(int)(WE / 4 / 256), 256, 0, stream>>>(Wk, wkb, (int)(WE / 4));
  convf<<<(int)(WE / 4 / 256), 256, 0, stream>>>(Wv, wvb, (int)(WE / 4));
  convf<<<(int)(WE / 4 / 256), 256, 0, stream>>>(Wo, wob, (int)(WE / 4));

  dim3 ggrid(S / 128, DM / 128);
  // Q projection -> bf16 row-major
  gemm_bt<1><<<ggrid, 256, 0, stream>>>(qb, wqb, bq, qpb, S, DM, DM);
  // K projection -> fp32 head-major straight into d_out key_ section
  gemm_bt<2><<<ggrid, 256, 0, stream>>>(kb, wkb, bk, keyO, S, DM, DM);
  // V projection -> fp32 head-major straight into d_out value section
  gemm_bt<2><<<ggrid, 256, 0, stream>>>(vb, wvb, bv, valO, S, DM, DM);

  pack_kb<<<(int)(NE / 256), 256, 0, stream>>>(keyO, kpb);
  transpose_v<<<16 * 64, 256, 0, stream>>>(valO, vt);

  attn<<<dim3(S / 64, 16), 256, 0, stream>>>(qpb, kpb, vt, ao);

  // output projection -> fp32 row-major into d_out
  gemm_bt<0><<<ggrid, 256, 0, stream>>>(ao, wob, bo, (void*)outO, S, DM, DM);
}

// Round 4
// 433.174 us; speedup vs baseline: 1.6394x; 1.6394x over previous
//
#include <hip/hip_runtime.h>
#include <math.h>

typedef __attribute__((ext_vector_type(8))) __bf16 bf16x8;
typedef __attribute__((ext_vector_type(4))) float f32x4;
typedef unsigned short ushort_t;
typedef unsigned int uint_t;

#define MFMA16(a,b,c) __builtin_amdgcn_mfma_f32_16x16x32_bf16(a,b,c,0,0,0)

#define GLD16(gp, lp) __builtin_amdgcn_global_load_lds( \
  (__attribute__((address_space(1))) const void*)(gp), \
  (__attribute__((address_space(3))) void*)(lp), 16, 0, 0)

__device__ __forceinline__ ushort_t f2bf(float f) {
  uint_t u = __builtin_bit_cast(uint_t, f);
  u = (u + 0x7fffu + ((u >> 16) & 1u)) >> 16;
  return (ushort_t)u;
}

// ---------------- fused fp32 -> bf16 convert (7 tensors, 1 launch) ----------------
struct ConvArgs {
  const float* src[7];
  ushort_t* dst[7];
  int cum[8];   // cumulative float4-counts
};

__global__ __launch_bounds__(256) void convall(ConvArgs a) {
  int flat = blockIdx.x * 256 + threadIdx.x;
  int s = 0;
#pragma unroll
  for (int i = 1; i < 7; ++i) if (flat >= a.cum[i]) s = i;
  int idx = flat - a.cum[s];
  float4 v = ((const float4*)a.src[s])[idx];
  ushort4 o;
  o.x = f2bf(v.x); o.y = f2bf(v.y); o.z = f2bf(v.z); o.w = f2bf(v.w);
  ((ushort4*)a.dst[s])[idx] = o;
}

// ---------------- fused QKV GEMM: C = A @ B^T + bias, z selects q/k/v ----------------
// z=0: out bf16 row-major scaled by 0.125*log2(e)  (Q for exp2-domain softmax)
// z=1: out fp32 head-major (key_) + bf16 row-major (attn K input)
// z=2: out fp32 head-major (value)
struct QKVArgs {
  const ushort_t* A[3];
  const ushort_t* B[3];
  const float* bias[3];
  float* outf[3];
  ushort_t* outb[3];
};

__global__ __launch_bounds__(256)
void qkv_gemm(QKVArgs ar) {
  const int M = 4096, N = 1024, K = 1024;
  const int z = blockIdx.z;
  const ushort_t* __restrict__ A = ar.A[z];
  const ushort_t* __restrict__ B = ar.B[z];
  const float* __restrict__ bias = ar.bias[z];

  __shared__ __align__(16) ushort_t Al[128 * 32];
  __shared__ __align__(16) ushort_t Bl[128 * 32];
  const int tid = threadIdx.x;
  const int w = tid >> 6, l = tid & 63;
  const int lr = l & 15, lg = l >> 4;
  const int bm = blockIdx.x * 128, bn = blockIdx.y * 128;
  const int wr = w >> 1, wc = w & 1;
  f32x4 acc[4][4] = {};

  const int crow = l >> 2;
  const int ccol = (l & 3) * 8;

  for (int k0 = 0; k0 < K; k0 += 32) {
    __syncthreads();
#pragma unroll
    for (int i = 0; i < 2; ++i) {
      const int c = w * 2 + i;
      GLD16(A + (size_t)(bm + c * 16 + crow) * K + k0 + ccol, &Al[c * 512]);
      GLD16(B + (size_t)(bn + c * 16 + crow) * K + k0 + ccol, &Bl[c * 512]);
    }
    __syncthreads();
    bf16x8 af[4], bfr[4];
#pragma unroll
    for (int mi = 0; mi < 4; ++mi)
      af[mi] = *(const bf16x8*)&Al[(wr * 64 + mi * 16 + lr) * 32 + lg * 8];
#pragma unroll
    for (int ni = 0; ni < 4; ++ni)
      bfr[ni] = *(const bf16x8*)&Bl[(wc * 64 + ni * 16 + lr) * 32 + lg * 8];
#pragma unroll
    for (int mi = 0; mi < 4; ++mi)
#pragma unroll
      for (int ni = 0; ni < 4; ++ni)
        acc[mi][ni] = MFMA16(af[mi], bfr[ni], acc[mi][ni]);
  }

  float* outf = ar.outf[z];
  ushort_t* outb = ar.outb[z];
#pragma unroll
  for (int mi = 0; mi < 4; ++mi) {
#pragma unroll
    for (int ni = 0; ni < 4; ++ni) {
      const int r0 = bm + wr * 64 + mi * 16 + lg * 4;
      const int cc = bn + wc * 64 + ni * 16 + lr;
      const float bv = bias[cc];
#pragma unroll
      for (int jj = 0; jj < 4; ++jj) {
        float v = acc[mi][ni][jj] + bv;
        int r = r0 + jj;
        if (z == 0) {
          outb[(size_t)r * N + cc] = f2bf(v * 0.18033688011112042f);
        } else {
          outf[((size_t)(cc >> 6) * M + r) * 64 + (cc & 63)] = v;
          if (z == 1) outb[(size_t)r * N + cc] = f2bf(v);
        }
      }
    }
  }
}

// ---------------- O-projection GEMM (fp32 row-major out) ----------------
__global__ __launch_bounds__(256)
void gemm_o(const ushort_t* __restrict__ A, const ushort_t* __restrict__ B,
            const float* __restrict__ bias, float* __restrict__ Cout)
{
  const int M = 4096, N = 1024, K = 1024;
  __shared__ __align__(16) ushort_t Al[128 * 32];
  __shared__ __align__(16) ushort_t Bl[128 * 32];
  const int tid = threadIdx.x;
  const int w = tid >> 6, l = tid & 63;
  const int lr = l & 15, lg = l >> 4;
  const int bm = blockIdx.x * 128, bn = blockIdx.y * 128;
  const int wr = w >> 1, wc = w & 1;
  f32x4 acc[4][4] = {};
  const int crow = l >> 2;
  const int ccol = (l & 3) * 8;

  for (int k0 = 0; k0 < K; k0 += 32) {
    __syncthreads();
#pragma unroll
    for (int i = 0; i < 2; ++i) {
      const int c = w * 2 + i;
      GLD16(A + (size_t)(bm + c * 16 + crow) * K + k0 + ccol, &Al[c * 512]);
      GLD16(B + (size_t)(bn + c * 16 + crow) * K + k0 + ccol, &Bl[c * 512]);
    }
    __syncthreads();
    bf16x8 af[4], bfr[4];
#pragma unroll
    for (int mi = 0; mi < 4; ++mi)
      af[mi] = *(const bf16x8*)&Al[(wr * 64 + mi * 16 + lr) * 32 + lg * 8];
#pragma unroll
    for (int ni = 0; ni < 4; ++ni)
      bfr[ni] = *(const bf16x8*)&Bl[(wc * 64 + ni * 16 + lr) * 32 + lg * 8];
#pragma unroll
    for (int mi = 0; mi < 4; ++mi)
#pragma unroll
      for (int ni = 0; ni < 4; ++ni)
        acc[mi][ni] = MFMA16(af[mi], bfr[ni], acc[mi][ni]);
  }

#pragma unroll
  for (int mi = 0; mi < 4; ++mi)
#pragma unroll
    for (int ni = 0; ni < 4; ++ni) {
      const int r0 = bm + wr * 64 + mi * 16 + lg * 4;
      const int cc = bn + wc * 64 + ni * 16 + lr;
      const float bv = bias[cc];
#pragma unroll
      for (int jj = 0; jj < 4; ++jj)
        Cout[(size_t)(r0 + jj) * N + cc] = acc[mi][ni][jj] + bv;
    }
}

// ---------------- transpose V: head-major fp32 [16][S][64] -> bf16 [1024][S] ----------------
__global__ __launch_bounds__(256) void transpose_v(const float* __restrict__ Vhead,
                                                   ushort_t* __restrict__ Vt) {
  const int S = 4096;
  __shared__ ushort_t t[64][72];
  int b = blockIdx.x;
  int h = b >> 6, st = (b & 63) * 64;
  int tid = threadIdx.x;
  int c = tid & 63, r4 = tid >> 6;
#pragma unroll
  for (int i = 0; i < 16; ++i) {
    int row = r4 + i * 4;
    t[row][c] = f2bf(Vhead[((size_t)h * S + st + row) * 64 + c]);
  }
  __syncthreads();
#pragma unroll
  for (int i = 0; i < 16; ++i) {
    int dk = r4 + i * 4;
    Vt[(size_t)(h * 64 + dk) * S + st + c] = t[c][dk];
  }
}

// ---------------- flash attention: 32 q/wave, 64-key steps, swapped operands ----------------
// Qb: bf16 [S][1024] (pre-scaled by 0.125*log2e), Kb: bf16 [S][1024],
// Vt: bf16 [1024][S], Ao: bf16 [S][1024]
__global__ __launch_bounds__(256)
void attn(const ushort_t* __restrict__ Qb, const ushort_t* __restrict__ Kb,
          const ushort_t* __restrict__ Vt, ushort_t* __restrict__ Ao) {
  const int S = 4096, DM = 1024;
  const int h = blockIdx.y;
  const int T = 31 - (int)blockIdx.x;          // longest q-tiles launch first
  const int tid = threadIdx.x, w = tid >> 6, l = tid & 63;
  const int lr = l & 15, lg = l >> 4;
  const int qw = T * 128 + w * 32;             // this wave's 32 q rows

  // per-wave P buffer: [32 q][80 cols] bf16 (64 keys + pad; 160B rows, 16B-aligned)
  __shared__ __align__(16) ushort_t plds[4][32 * 80];
  ushort_t* pw = plds[w];

  const ushort_t* __restrict__ Kh = Kb + h * 64;
  const ushort_t* __restrict__ Qh = Qb + h * 64;
  const ushort_t* __restrict__ Vh = Vt + (size_t)h * 64 * S;

  // Q fragments (B-operand of swapped QK): [qt][dslice]; lane holds q=qt*16+lr
  bf16x8 qf[2][2];
#pragma unroll
  for (int qt = 0; qt < 2; ++qt)
#pragma unroll
    for (int d = 0; d < 2; ++d)
      qf[qt][d] = *(const bf16x8*)&Qh[(size_t)(qw + qt * 16 + lr) * DM + d * 32 + lg * 8];

  f32x4 o[2][4] = {};          // [qt][dvt]; col(lane&15)=q, row(lg*4+jj)=dv
  float m[2], lsum[2];
#pragma unroll
  for (int qt = 0; qt < 2; ++qt) { m[qt] = -__builtin_inff(); lsum[qt] = 0.0f; }

  auto step = [&](int kt, bool domask) {
    // ---- QK^T (swapped): St[key][q]; lane: q=qt*16+lr, keys=kt4*16+lg*4+jj
    f32x4 st[4][2];
#pragma unroll
    for (int kt4 = 0; kt4 < 4; ++kt4) {
      bf16x8 k0 = *(const bf16x8*)&Kh[(size_t)(kt + kt4 * 16 + lr) * DM + lg * 8];
      bf16x8 k1 = *(const bf16x8*)&Kh[(size_t)(kt + kt4 * 16 + lr) * DM + 32 + lg * 8];
      f32x4 c0 = {}, c1 = {};
      c0 = MFMA16(k0, qf[0][0], c0);
      c0 = MFMA16(k1, qf[0][1], c0);
      c1 = MFMA16(k0, qf[1][0], c1);
      c1 = MFMA16(k1, qf[1][1], c1);
      st[kt4][0] = c0;
      st[kt4][1] = c1;
    }
    if (domask) {
#pragma unroll
      for (int kt4 = 0; kt4 < 4; ++kt4)
#pragma unroll
        for (int qt = 0; qt < 2; ++qt) {
          int qq = qw + qt * 16 + lr;
#pragma unroll
          for (int jj = 0; jj < 4; ++jj) {
            int key = kt + kt4 * 16 + lg * 4 + jj;
            if (key > qq) st[kt4][qt][jj] = -__builtin_inff();
          }
        }
    }
    // ---- online softmax (exp2 domain; scale folded into Q)
#pragma unroll
    for (int qt = 0; qt < 2; ++qt) {
      float pm = -__builtin_inff();
#pragma unroll
      for (int kt4 = 0; kt4 < 4; ++kt4)
#pragma unroll
        for (int jj = 0; jj < 4; ++jj)
          pm = fmaxf(pm, st[kt4][qt][jj]);
      pm = fmaxf(pm, __shfl_xor(pm, 16));
      pm = fmaxf(pm, __shfl_xor(pm, 32));
      float mn = fmaxf(m[qt], pm);
      float al = __builtin_amdgcn_exp2f(m[qt] - mn);
      m[qt] = mn;
      float ps = 0.0f;
#pragma unroll
      for (int kt4 = 0; kt4 < 4; ++kt4) {
#pragma unroll
        for (int jj = 0; jj < 4; ++jj) {
          float e = __builtin_amdgcn_exp2f(st[kt4][qt][jj] - mn);
          st[kt4][qt][jj] = e;
          ps += e;
        }
      }
      ps += __shfl_xor(ps, 16);
      ps += __shfl_xor(ps, 32);
      lsum[qt] = lsum[qt] * al + ps;
#pragma unroll
      for (int dvt = 0; dvt < 4; ++dvt) {
#pragma unroll
        for (int jj = 0; jj < 4; ++jj) o[qt][dvt][jj] *= al;
      }
      // write P tile rows to per-wave LDS (4 consecutive keys -> 8B store)
#pragma unroll
      for (int kt4 = 0; kt4 < 4; ++kt4) {
        ushort4 pk;
        pk.x = f2bf(st[kt4][qt][0]); pk.y = f2bf(st[kt4][qt][1]);
        pk.z = f2bf(st[kt4][qt][2]); pk.w = f2bf(st[kt4][qt][3]);
        *(ushort4*)&pw[(qt * 16 + lr) * 80 + kt4 * 16 + lg * 4] = pk;
      }
    }
    // ---- P fragments (B-operand of swapped PV): lane q=lr, keys ks*32+lg*8..
    bf16x8 pa[2][2];
#pragma unroll
    for (int qt = 0; qt < 2; ++qt)
#pragma unroll
      for (int ks = 0; ks < 2; ++ks)
        pa[qt][ks] = *(const bf16x8*)&pw[(qt * 16 + lr) * 80 + ks * 32 + lg * 8];
    // ---- PV (swapped): O[dv][q]; A=V^T rows (dv), B=P rows (q)
#pragma unroll
    for (int dvt = 0; dvt < 4; ++dvt) {
#pragma unroll
      for (int ks = 0; ks < 2; ++ks) {
        bf16x8 vf = *(const bf16x8*)&Vh[(size_t)(dvt * 16 + lr) * S + kt + ks * 32 + lg * 8];
        o[0][dvt] = MFMA16(vf, pa[0][ks], o[0][dvt]);
        o[1][dvt] = MFMA16(vf, pa[1][ks], o[1][dvt]);
      }
    }
  };

  const int ktm = qw & ~63;          // start of the (single) masked step
  for (int kt = 0; kt < ktm; kt += 64) step(kt, false);
  step(ktm, true);

  // ---- epilogue: divide by lsum (same lane layout: q = lane&15), pack, store
#pragma unroll
  for (int qt = 0; qt < 2; ++qt) {
    float inv = 1.0f / lsum[qt];
#pragma unroll
    for (int dvt = 0; dvt < 4; ++dvt) {
      ushort4 pk;
      pk.x = f2bf(o[qt][dvt][0] * inv);
      pk.y = f2bf(o[qt][dvt][1] * inv);
      pk.z = f2bf(o[qt][dvt][2] * inv);
      pk.w = f2bf(o[qt][dvt][3] * inv);
      *(ushort4*)&Ao[(size_t)(qw + qt * 16 + lr) * DM + h * 64 + dvt * 16 + lg * 4] = pk;
    }
  }
}

// ---------------- launch ----------------
extern "C" void kernel_launch(void* const* d_in, const int* in_sizes, int n_in,
                              void* d_out, int out_size, void* d_ws, size_t ws_size,
                              hipStream_t stream) {
  const int S = 4096, DM = 1024;
  const size_t NE = (size_t)S * DM;

  const float* q  = (const float*)d_in[0];
  const float* k  = (const float*)d_in[1];
  const float* v  = (const float*)d_in[2];
  const float* Wq = (const float*)d_in[3];
  const float* bq = (const float*)d_in[4];
  const float* Wk = (const float*)d_in[5];
  const float* bk = (const float*)d_in[6];
  const float* Wv = (const float*)d_in[7];
  const float* bv = (const float*)d_in[8];
  const float* Wo = (const float*)d_in[9];
  const float* bo = (const float*)d_in[10];

  // workspace (48 MB high-water):
  //  [0,8M)   qb   (dead after qkv_gemm) -> ao overlay
  //  [8,16M)  kb   (dead after qkv_gemm) -> vt overlay
  //  [16,24M) vb
  //  [24,32M) wqb/wkb/wvb/wob
  //  [32,40M) qpb
  //  [40,48M) kpb
  unsigned char* ws = (unsigned char*)d_ws;
  ushort_t* qb  = (ushort_t*)(ws);
  ushort_t* kb  = (ushort_t*)(ws + (8u << 20));
  ushort_t* vb  = (ushort_t*)(ws + (16u << 20));
  ushort_t* wqb = (ushort_t*)(ws + (24u << 20));
  ushort_t* wkb = (ushort_t*)(ws + (26u << 20));
  ushort_t* wvb = (ushort_t*)(ws + (28u << 20));
  ushort_t* wob = (ushort_t*)(ws + (30u << 20));
  ushort_t* qpb = (ushort_t*)(ws + (32u << 20));
  ushort_t* kpb = (ushort_t*)(ws + (40u << 20));
  ushort_t* vt  = kb;   // overlay
  ushort_t* ao  = qb;   // overlay

  float* outO = (float*)d_out;
  float* keyO = outO + NE;
  float* valO = keyO + NE;

  // 1) fused fp32->bf16 conversion (7 tensors)
  ConvArgs ca;
  ca.src[0] = q;  ca.src[1] = k;  ca.src[2] = v;
  ca.src[3] = Wq; ca.src[4] = Wk; ca.src[5] = Wv; ca.src[6] = Wo;
  ca.dst[0] = qb;  ca.dst[1] = kb;  ca.dst[2] = vb;
  ca.dst[3] = wqb; ca.dst[4] = wkb; ca.dst[5] = wvb; ca.dst[6] = wob;
  const int NB = 1048576, WB = 262144;
  ca.cum[0] = 0;
  ca.cum[1] = NB; ca.cum[2] = 2 * NB; ca.cum[3] = 3 * NB;
  ca.cum[4] = 3 * NB + WB; ca.cum[5] = 3 * NB + 2 * WB;
  ca.cum[6] = 3 * NB + 3 * WB; ca.cum[7] = 3 * NB + 4 * WB;
  convall<<<ca.cum[7] / 256, 256, 0, stream>>>(ca);

  // 2) fused QKV projections
  QKVArgs qa;
  qa.A[0] = qb;  qa.A[1] = kb;  qa.A[2] = vb;
  qa.B[0] = wqb; qa.B[1] = wkb; qa.B[2] = wvb;
  qa.bias[0] = bq; qa.bias[1] = bk; qa.bias[2] = bv;
  qa.outf[0] = nullptr; qa.outf[1] = keyO; qa.outf[2] = valO;
  qa.outb[0] = qpb;     qa.outb[1] = kpb;  qa.outb[2] = nullptr;
  qkv_gemm<<<dim3(S / 128, DM / 128, 3), 256, 0, stream>>>(qa);

  // 3) V transpose for PV B-operand
  transpose_v<<<16 * 64, 256, 0, stream>>>(valO, vt);

  // 4) flash attention
  attn<<<dim3(S / 128, 16), 256, 0, stream>>>(qpb, kpb, vt, ao);

  // 5) output projection
  gemm_o<<<dim3(S / 128, DM / 128), 256, 0, stream>>>(ao, wob, bo, outO);
}

// Round 5
// 315.340 us; speedup vs baseline: 2.2521x; 1.3737x over previous
//
#include <hip/hip_runtime.h>
#include <math.h>

typedef __attribute__((ext_vector_type(8))) __bf16 bf16x8;
typedef __attribute__((ext_vector_type(8))) unsigned short ushort8;
typedef __attribute__((ext_vector_type(4))) float f32x4;
typedef unsigned short ushort_t;
typedef unsigned int uint_t;

#define MFMA16(a,b,c) __builtin_amdgcn_mfma_f32_16x16x32_bf16(a,b,c,0,0,0)

#define GLD16(gp, lp) __builtin_amdgcn_global_load_lds( \
  (__attribute__((address_space(1))) const void*)(gp), \
  (__attribute__((address_space(3))) void*)(lp), 16, 0, 0)

__device__ __forceinline__ ushort_t f2bf(float f) {
  uint_t u = __builtin_bit_cast(uint_t, f);
  u = (u + 0x7fffu + ((u >> 16) & 1u)) >> 16;
  return (ushort_t)u;
}

// ---------------- fused fp32 -> bf16 convert (7 tensors, 1 launch) ----------------
struct ConvArgs {
  const float* src[7];
  ushort_t* dst[7];
  int cum[8];   // cumulative float4-counts
};

__global__ __launch_bounds__(256) void convall(ConvArgs a) {
  int flat = blockIdx.x * 256 + threadIdx.x;
  int s = 0;
#pragma unroll
  for (int i = 1; i < 7; ++i) if (flat >= a.cum[i]) s = i;
  int idx = flat - a.cum[s];
  float4 v = ((const float4*)a.src[s])[idx];
  ushort4 o;
  o.x = f2bf(v.x); o.y = f2bf(v.y); o.z = f2bf(v.z); o.w = f2bf(v.w);
  ((ushort4*)a.dst[s])[idx] = o;
}

// ---------------- fused QKV GEMM: C = A @ B^T + bias, z selects q/k/v ----------------
// Tiled fragment layout for attention (1KB tiles, MFMA lane order):
//   Q/K: idx = ((h*256 + s/16)*2 + dk/32)*512 + ((s&15) + 16*((dk&31)>>3))*8 + (dk&7)
// z=0: Q -> tiled bf16, scaled by 0.125*log2(e)
// z=1: K -> fp32 head-major (key_ output) + tiled bf16
// z=2: V -> fp32 head-major (value output)
struct QKVArgs {
  const ushort_t* A[3];
  const ushort_t* B[3];
  const float* bias[3];
  float* outf[3];
  ushort_t* outb[3];
};

__global__ __launch_bounds__(256)
void qkv_gemm(QKVArgs ar) {
  const int M = 4096, K = 1024;
  const int z = blockIdx.z;
  const ushort_t* __restrict__ A = ar.A[z];
  const ushort_t* __restrict__ B = ar.B[z];
  const float* __restrict__ bias = ar.bias[z];

  __shared__ __align__(16) ushort_t Al[128 * 32];
  __shared__ __align__(16) ushort_t Bl[128 * 32];
  const int tid = threadIdx.x;
  const int w = tid >> 6, l = tid & 63;
  const int lr = l & 15, lg = l >> 4;
  const int bm = blockIdx.x * 128, bn = blockIdx.y * 128;
  const int wr = w >> 1, wc = w & 1;
  f32x4 acc[4][4] = {};

  const int crow = l >> 2;
  const int ccol = (l & 3) * 8;

  for (int k0 = 0; k0 < K; k0 += 32) {
    __syncthreads();
#pragma unroll
    for (int i = 0; i < 2; ++i) {
      const int c = w * 2 + i;
      GLD16(A + (size_t)(bm + c * 16 + crow) * K + k0 + ccol, &Al[c * 512]);
      GLD16(B + (size_t)(bn + c * 16 + crow) * K + k0 + ccol, &Bl[c * 512]);
    }
    __syncthreads();
    bf16x8 af[4], bfr[4];
#pragma unroll
    for (int mi = 0; mi < 4; ++mi)
      af[mi] = *(const bf16x8*)&Al[(wr * 64 + mi * 16 + lr) * 32 + lg * 8];
#pragma unroll
    for (int ni = 0; ni < 4; ++ni)
      bfr[ni] = *(const bf16x8*)&Bl[(wc * 64 + ni * 16 + lr) * 32 + lg * 8];
#pragma unroll
    for (int mi = 0; mi < 4; ++mi)
#pragma unroll
      for (int ni = 0; ni < 4; ++ni)
        acc[mi][ni] = MFMA16(af[mi], bfr[ni], acc[mi][ni]);
  }

  float* outf = ar.outf[z];
  ushort_t* outb = ar.outb[z];
#pragma unroll
  for (int mi = 0; mi < 4; ++mi) {
#pragma unroll
    for (int ni = 0; ni < 4; ++ni) {
      const int r0 = bm + wr * 64 + mi * 16 + lg * 4;
      const int cc = bn + wc * 64 + ni * 16 + lr;
      const float bv = bias[cc];
      const int hh = cc >> 6, dk = cc & 63;
      const int dh = dk >> 5, lgk = (dk & 31) >> 3, jq = dk & 7;
#pragma unroll
      for (int jj = 0; jj < 4; ++jj) {
        float v = acc[mi][ni][jj] + bv;
        int s = r0 + jj;
        if (z == 0) {
          size_t idx = ((((size_t)hh * 256 + (s >> 4)) * 2 + dh) * 64 + (s & 15) + 16 * lgk) * 8 + jq;
          outb[idx] = f2bf(v * 0.18033688011112042f);
        } else if (z == 1) {
          outf[((size_t)hh * M + s) * 64 + dk] = v;
          size_t idx = ((((size_t)hh * 256 + (s >> 4)) * 2 + dh) * 64 + (s & 15) + 16 * lgk) * 8 + jq;
          outb[idx] = f2bf(v);
        } else {
          outf[((size_t)hh * M + s) * 64 + dk] = v;
        }
      }
    }
  }
}

// ---------------- O-projection GEMM (fp32 row-major out) ----------------
__global__ __launch_bounds__(256)
void gemm_o(const ushort_t* __restrict__ A, const ushort_t* __restrict__ B,
            const float* __restrict__ bias, float* __restrict__ Cout)
{
  const int N = 1024, K = 1024;
  __shared__ __align__(16) ushort_t Al[128 * 32];
  __shared__ __align__(16) ushort_t Bl[128 * 32];
  const int tid = threadIdx.x;
  const int w = tid >> 6, l = tid & 63;
  const int lr = l & 15, lg = l >> 4;
  const int bm = blockIdx.x * 128, bn = blockIdx.y * 128;
  const int wr = w >> 1, wc = w & 1;
  f32x4 acc[4][4] = {};
  const int crow = l >> 2;
  const int ccol = (l & 3) * 8;

  for (int k0 = 0; k0 < K; k0 += 32) {
    __syncthreads();
#pragma unroll
    for (int i = 0; i < 2; ++i) {
      const int c = w * 2 + i;
      GLD16(A + (size_t)(bm + c * 16 + crow) * K + k0 + ccol, &Al[c * 512]);
      GLD16(B + (size_t)(bn + c * 16 + crow) * K + k0 + ccol, &Bl[c * 512]);
    }
    __syncthreads();
    bf16x8 af[4], bfr[4];
#pragma unroll
    for (int mi = 0; mi < 4; ++mi)
      af[mi] = *(const bf16x8*)&Al[(wr * 64 + mi * 16 + lr) * 32 + lg * 8];
#pragma unroll
    for (int ni = 0; ni < 4; ++ni)
      bfr[ni] = *(const bf16x8*)&Bl[(wc * 64 + ni * 16 + lr) * 32 + lg * 8];
#pragma unroll
    for (int mi = 0; mi < 4; ++mi)
#pragma unroll
      for (int ni = 0; ni < 4; ++ni)
        acc[mi][ni] = MFMA16(af[mi], bfr[ni], acc[mi][ni]);
  }

#pragma unroll
  for (int mi = 0; mi < 4; ++mi)
#pragma unroll
    for (int ni = 0; ni < 4; ++ni) {
      const int r0 = bm + wr * 64 + mi * 16 + lg * 4;
      const int cc = bn + wc * 64 + ni * 16 + lr;
      const float bv = bias[cc];
#pragma unroll
      for (int jj = 0; jj < 4; ++jj)
        Cout[(size_t)(r0 + jj) * N + cc] = acc[mi][ni][jj] + bv;
    }
}

// ---------------- pack V: head-major fp32 [16][S][64] -> tiled bf16 V^T ----------------
// tile idx = ((h*128 + s/32)*4 + dv/16); element (l = (dv&15) + 16*((s&31)>>3), j = s&7)
__global__ __launch_bounds__(256) void pack_vt(const float* __restrict__ Vhead,
                                               ushort_t* __restrict__ Vt) {
  const int S = 4096;
  int tile = blockIdx.x * 4 + (threadIdx.x >> 6);   // 8192 tiles
  int l = threadIdx.x & 63;
  int h = tile >> 9, rem = tile & 511;
  int kb = rem >> 2, dvt = rem & 3;
  int lr = l & 15, lg = l >> 4;
  const float* src = Vhead + ((size_t)h * S + kb * 32 + lg * 8) * 64 + dvt * 16 + lr;
  ushort8 o8;
#pragma unroll
  for (int j = 0; j < 8; ++j) o8[j] = f2bf(src[(size_t)j * 64]);
  *(ushort8*)&Vt[(size_t)tile * 512 + l * 8] = o8;
}

// ---------------- flash attention: tiled-fragment loads, K prefetch ----------------
// Qt/Kt: tiled bf16 (Q pre-scaled by 0.125*log2e), Vt: tiled bf16 V^T,
// Ao: bf16 [S][1024]
__global__ __launch_bounds__(256, 2)
void attn(const ushort_t* __restrict__ Qt, const ushort_t* __restrict__ Kt,
          const ushort_t* __restrict__ Vt, ushort_t* __restrict__ Ao) {
  const int DM = 1024;
  const int h = blockIdx.y;
  const int T = 31 - (int)blockIdx.x;          // longest q-tiles launch first
  const int tid = threadIdx.x, w = tid >> 6, l = tid & 63;
  const int lr = l & 15, lg = l >> 4;
  const int qw = T * 128 + w * 32;             // this wave's 32 q rows

  // per-wave P buffer: [32 rows][64 cols] bf16, XOR-swizzled (conflict-free)
  __shared__ __align__(16) ushort_t plds[4][32 * 64];
  char* pw = (char*)plds[w];
  const uint_t swz = (uint_t)(lr & 7) << 4;

  const size_t hQ = (size_t)h * 256;

  // Q fragments (B-operand of swapped QK): lane q = l&15
  bf16x8 qf[2][2];
#pragma unroll
  for (int qt = 0; qt < 2; ++qt)
#pragma unroll
    for (int dh = 0; dh < 2; ++dh)
      qf[qt][dh] = *(const bf16x8*)&Qt[(((hQ + (qw >> 4) + qt) * 2 + dh) << 9) + l * 8];

  f32x4 o[2][4] = {};          // [qt][dvt]; col(l&15)=q, row(lg*4+jj)=dv
  float m[2], lsum[2];
#pragma unroll
  for (int qt = 0; qt < 2; ++qt) { m[qt] = -__builtin_inff(); lsum[qt] = 0.0f; }

  bf16x8 kc[8], kn[8], vf[8];

  auto loadK8 = [&](bf16x8* dst, int kt) {
#pragma unroll
    for (int kt4 = 0; kt4 < 4; ++kt4)
#pragma unroll
      for (int dh = 0; dh < 2; ++dh)
        dst[kt4 * 2 + dh] =
            *(const bf16x8*)&Kt[(((hQ + (kt >> 4) + kt4) * 2 + dh) << 9) + l * 8];
  };
  auto loadV8 = [&](int kt) {
#pragma unroll
    for (int ks = 0; ks < 2; ++ks)
#pragma unroll
      for (int dvt = 0; dvt < 4; ++dvt)
        vf[ks * 4 + dvt] =
            *(const bf16x8*)&Vt[((((size_t)h * 128 + (kt >> 5) + ks) * 4 + dvt) << 9) + l * 8];
  };

  auto step = [&](int kt, bool domask, bool pf) {
    loadV8(kt);                       // early-issue V (used after softmax)
    if (pf) loadK8(kn, kt + 64);      // cross-step K prefetch
    // ---- QK^T (swapped): st[kt4][qt]; lane: q=l&15, key=kt+kt4*16+lg*4+jj
    f32x4 st[4][2];
#pragma unroll
    for (int kt4 = 0; kt4 < 4; ++kt4) {
      f32x4 c0 = {}, c1 = {};
      c0 = MFMA16(kc[kt4 * 2 + 0], qf[0][0], c0);
      c0 = MFMA16(kc[kt4 * 2 + 1], qf[0][1], c0);
      c1 = MFMA16(kc[kt4 * 2 + 0], qf[1][0], c1);
      c1 = MFMA16(kc[kt4 * 2 + 1], qf[1][1], c1);
      st[kt4][0] = c0;
      st[kt4][1] = c1;
    }
    if (domask) {
#pragma unroll
      for (int kt4 = 0; kt4 < 4; ++kt4)
#pragma unroll
        for (int qt = 0; qt < 2; ++qt) {
          int qq = qw + qt * 16 + lr;
#pragma unroll
          for (int jj = 0; jj < 4; ++jj) {
            int key = kt + kt4 * 16 + lg * 4 + jj;
            if (key > qq) st[kt4][qt][jj] = -__builtin_inff();
          }
        }
    }
    // ---- online softmax (exp2 domain; scale folded into Q)
#pragma unroll
    for (int qt = 0; qt < 2; ++qt) {
      float pm = -__builtin_inff();
#pragma unroll
      for (int kt4 = 0; kt4 < 4; ++kt4)
#pragma unroll
        for (int jj = 0; jj < 4; ++jj)
          pm = fmaxf(pm, st[kt4][qt][jj]);
      pm = fmaxf(pm, __shfl_xor(pm, 16));
      pm = fmaxf(pm, __shfl_xor(pm, 32));
      float mn = fmaxf(m[qt], pm);
      float al = __builtin_amdgcn_exp2f(m[qt] - mn);
      m[qt] = mn;
      float ps = 0.0f;
#pragma unroll
      for (int kt4 = 0; kt4 < 4; ++kt4) {
#pragma unroll
        for (int jj = 0; jj < 4; ++jj) {
          float e = __builtin_amdgcn_exp2f(st[kt4][qt][jj] - mn);
          st[kt4][qt][jj] = e;
          ps += e;
        }
      }
      ps += __shfl_xor(ps, 16);
      ps += __shfl_xor(ps, 32);
      lsum[qt] = lsum[qt] * al + ps;
#pragma unroll
      for (int dvt = 0; dvt < 4; ++dvt) {
#pragma unroll
        for (int jj = 0; jj < 4; ++jj) o[qt][dvt][jj] *= al;
      }
      // write P rows to swizzled LDS (8B stores)
#pragma unroll
      for (int kt4 = 0; kt4 < 4; ++kt4) {
        ushort4 pk;
        pk.x = f2bf(st[kt4][qt][0]); pk.y = f2bf(st[kt4][qt][1]);
        pk.z = f2bf(st[kt4][qt][2]); pk.w = f2bf(st[kt4][qt][3]);
        uint_t bo = (uint_t)(qt * 16 + lr) * 128 + (uint_t)(kt4 * 32 + lg * 8);
        *(ushort4*)(pw + (bo ^ swz)) = pk;
      }
    }
    // ---- P fragments (B-operand of swapped PV)
    bf16x8 pa[2][2];
#pragma unroll
    for (int qt = 0; qt < 2; ++qt)
#pragma unroll
      for (int ks = 0; ks < 2; ++ks) {
        uint_t bo = (uint_t)(qt * 16 + lr) * 128 + (uint_t)(ks * 64 + lg * 16);
        pa[qt][ks] = *(const bf16x8*)(pw + (bo ^ swz));
      }
    // ---- PV (swapped): O[dv][q]
#pragma unroll
    for (int dvt = 0; dvt < 4; ++dvt)
#pragma unroll
      for (int ks = 0; ks < 2; ++ks) {
        o[0][dvt] = MFMA16(vf[ks * 4 + dvt], pa[0][ks], o[0][dvt]);
        o[1][dvt] = MFMA16(vf[ks * 4 + dvt], pa[1][ks], o[1][dvt]);
      }
    if (pf) {
#pragma unroll
      for (int i = 0; i < 8; ++i) kc[i] = kn[i];
    }
  };

  const int ktm = qw & ~63;          // start of the (single) masked step
  loadK8(kc, 0);
  for (int kt = 0; kt < ktm; kt += 64) step(kt, false, true);
  step(ktm, true, false);

  // ---- epilogue: divide by lsum (q = l&15), pack, store row-major
#pragma unroll
  for (int qt = 0; qt < 2; ++qt) {
    float inv = 1.0f / lsum[qt];
#pragma unroll
    for (int dvt = 0; dvt < 4; ++dvt) {
      ushort4 pk;
      pk.x = f2bf(o[qt][dvt][0] * inv);
      pk.y = f2bf(o[qt][dvt][1] * inv);
      pk.z = f2bf(o[qt][dvt][2] * inv);
      pk.w = f2bf(o[qt][dvt][3] * inv);
      *(ushort4*)&Ao[(size_t)(qw + qt * 16 + lr) * DM + h * 64 + dvt * 16 + lg * 4] = pk;
    }
  }
}

// ---------------- launch ----------------
extern "C" void kernel_launch(void* const* d_in, const int* in_sizes, int n_in,
                              void* d_out, int out_size, void* d_ws, size_t ws_size,
                              hipStream_t stream) {
  const int S = 4096, DM = 1024;
  const size_t NE = (size_t)S * DM;

  const float* q  = (const float*)d_in[0];
  const float* k  = (const float*)d_in[1];
  const float* v  = (const float*)d_in[2];
  const float* Wq = (const float*)d_in[3];
  const float* bq = (const float*)d_in[4];
  const float* Wk = (const float*)d_in[5];
  const float* bk = (const float*)d_in[6];
  const float* Wv = (const float*)d_in[7];
  const float* bv = (const float*)d_in[8];
  const float* Wo = (const float*)d_in[9];
  const float* bo = (const float*)d_in[10];

  // workspace (48 MB high-water):
  //  [0,8M)   qb   (dead after qkv_gemm) -> ao overlay
  //  [8,16M)  kb   (dead after qkv_gemm) -> vt overlay (tiled V^T)
  //  [16,24M) vb
  //  [24,32M) wqb/wkb/wvb/wob
  //  [32,40M) qpb (tiled Q)
  //  [40,48M) kpb (tiled K)
  unsigned char* ws = (unsigned char*)d_ws;
  ushort_t* qb  = (ushort_t*)(ws);
  ushort_t* kb  = (ushort_t*)(ws + (8u << 20));
  ushort_t* vb  = (ushort_t*)(ws + (16u << 20));
  ushort_t* wqb = (ushort_t*)(ws + (24u << 20));
  ushort_t* wkb = (ushort_t*)(ws + (26u << 20));
  ushort_t* wvb = (ushort_t*)(ws + (28u << 20));
  ushort_t* wob = (ushort_t*)(ws + (30u << 20));
  ushort_t* qpb = (ushort_t*)(ws + (32u << 20));
  ushort_t* kpb = (ushort_t*)(ws + (40u << 20));
  ushort_t* vt  = kb;   // overlay
  ushort_t* ao  = qb;   // overlay

  float* outO = (float*)d_out;
  float* keyO = outO + NE;
  float* valO = keyO + NE;

  // 1) fused fp32->bf16 conversion (7 tensors)
  ConvArgs ca;
  ca.src[0] = q;  ca.src[1] = k;  ca.src[2] = v;
  ca.src[3] = Wq; ca.src[4] = Wk; ca.src[5] = Wv; ca.src[6] = Wo;
  ca.dst[0] = qb;  ca.dst[1] = kb;  ca.dst[2] = vb;
  ca.dst[3] = wqb; ca.dst[4] = wkb; ca.dst[5] = wvb; ca.dst[6] = wob;
  const int NB = 1048576, WB = 262144;
  ca.cum[0] = 0;
  ca.cum[1] = NB; ca.cum[2] = 2 * NB; ca.cum[3] = 3 * NB;
  ca.cum[4] = 3 * NB + WB; ca.cum[5] = 3 * NB + 2 * WB;
  ca.cum[6] = 3 * NB + 3 * WB; ca.cum[7] = 3 * NB + 4 * WB;
  convall<<<ca.cum[7] / 256, 256, 0, stream>>>(ca);

  // 2) fused QKV projections (Q/K write tiled bf16; K/V write fp32 head-major)
  QKVArgs qa;
  qa.A[0] = qb;  qa.A[1] = kb;  qa.A[2] = vb;
  qa.B[0] = wqb; qa.B[1] = wkb; qa.B[2] = wvb;
  qa.bias[0] = bq; qa.bias[1] = bk; qa.bias[2] = bv;
  qa.outf[0] = nullptr; qa.outf[1] = keyO; qa.outf[2] = valO;
  qa.outb[0] = qpb;     qa.outb[1] = kpb;  qa.outb[2] = nullptr;
  qkv_gemm<<<dim3(S / 128, DM / 128, 3), 256, 0, stream>>>(qa);

  // 3) pack V -> tiled bf16 V^T
  pack_vt<<<2048, 256, 0, stream>>>(valO, vt);

  // 4) flash attention
  attn<<<dim3(S / 128, 16), 256, 0, stream>>>(qpb, kpb, vt, ao);

  // 5) output projection
  gemm_o<<<dim3(S / 128, DM / 128), 256, 0, stream>>>(ao, wob, bo, outO);
}

// Round 6
// 306.302 us; speedup vs baseline: 2.3185x; 1.0295x over previous
//
#include <hip/hip_runtime.h>
#include <math.h>

typedef __attribute__((ext_vector_type(8))) __bf16 bf16x8;
typedef __attribute__((ext_vector_type(8))) unsigned short ushort8;
typedef __attribute__((ext_vector_type(4))) float f32x4;
typedef unsigned short ushort_t;
typedef unsigned int uint_t;

#define MFMA16(a,b,c) __builtin_amdgcn_mfma_f32_16x16x32_bf16(a,b,c,0,0,0)

#define GLD16(gp, lp) __builtin_amdgcn_global_load_lds( \
  (__attribute__((address_space(1))) const void*)(gp), \
  (__attribute__((address_space(3))) void*)(lp), 16, 0, 0)

__device__ __forceinline__ ushort_t f2bf(float f) {
  uint_t u = __builtin_bit_cast(uint_t, f);
  u = (u + 0x7fffu + ((u >> 16) & 1u)) >> 16;
  return (ushort_t)u;
}
// native cast (compiler emits v_cvt_pk_bf16_f32 for pairs)
__device__ __forceinline__ ushort_t f2bfn(float f) {
  __bf16 b = (__bf16)f;
  return __builtin_bit_cast(ushort_t, b);
}

// ---------------- fused fp32 -> bf16 convert (7 tensors, 1 launch) ----------------
struct ConvArgs {
  const float* src[7];
  ushort_t* dst[7];
  int cum[8];   // cumulative float4-counts
};

__global__ __launch_bounds__(256) void convall(ConvArgs a) {
  int flat = blockIdx.x * 256 + threadIdx.x;
  int s = 0;
#pragma unroll
  for (int i = 1; i < 7; ++i) if (flat >= a.cum[i]) s = i;
  int idx = flat - a.cum[s];
  float4 v = ((const float4*)a.src[s])[idx];
  ushort4 o;
  o.x = f2bf(v.x); o.y = f2bf(v.y); o.z = f2bf(v.z); o.w = f2bf(v.w);
  ((ushort4*)a.dst[s])[idx] = o;
}

// ---------------- fused QKV GEMM: C = A @ B^T + bias, z selects q/k/v ----------------
// Tiled fragment layout for attention (1KB tiles, MFMA lane order):
//   Q/K: idx = ((h*256 + s/16)*2 + dk/32)*512 + ((s&15) + 16*((dk&31)>>3))*8 + (dk&7)
struct QKVArgs {
  const ushort_t* A[3];
  const ushort_t* B[3];
  const float* bias[3];
  float* outf[3];
  ushort_t* outb[3];
};

__global__ __launch_bounds__(256)
void qkv_gemm(QKVArgs ar) {
  const int M = 4096, K = 1024;
  const int z = blockIdx.z;
  const ushort_t* __restrict__ A = ar.A[z];
  const ushort_t* __restrict__ B = ar.B[z];
  const float* __restrict__ bias = ar.bias[z];

  __shared__ __align__(16) ushort_t Al[128 * 32];
  __shared__ __align__(16) ushort_t Bl[128 * 32];
  const int tid = threadIdx.x;
  const int w = tid >> 6, l = tid & 63;
  const int lr = l & 15, lg = l >> 4;
  const int bm = blockIdx.x * 128, bn = blockIdx.y * 128;
  const int wr = w >> 1, wc = w & 1;
  f32x4 acc[4][4] = {};

  const int crow = l >> 2;
  const int ccol = (l & 3) * 8;

  for (int k0 = 0; k0 < K; k0 += 32) {
    __syncthreads();
#pragma unroll
    for (int i = 0; i < 2; ++i) {
      const int c = w * 2 + i;
      GLD16(A + (size_t)(bm + c * 16 + crow) * K + k0 + ccol, &Al[c * 512]);
      GLD16(B + (size_t)(bn + c * 16 + crow) * K + k0 + ccol, &Bl[c * 512]);
    }
    __syncthreads();
    bf16x8 af[4], bfr[4];
#pragma unroll
    for (int mi = 0; mi < 4; ++mi)
      af[mi] = *(const bf16x8*)&Al[(wr * 64 + mi * 16 + lr) * 32 + lg * 8];
#pragma unroll
    for (int ni = 0; ni < 4; ++ni)
      bfr[ni] = *(const bf16x8*)&Bl[(wc * 64 + ni * 16 + lr) * 32 + lg * 8];
#pragma unroll
    for (int mi = 0; mi < 4; ++mi)
#pragma unroll
      for (int ni = 0; ni < 4; ++ni)
        acc[mi][ni] = MFMA16(af[mi], bfr[ni], acc[mi][ni]);
  }

  float* outf = ar.outf[z];
  ushort_t* outb = ar.outb[z];
#pragma unroll
  for (int mi = 0; mi < 4; ++mi) {
#pragma unroll
    for (int ni = 0; ni < 4; ++ni) {
      const int r0 = bm + wr * 64 + mi * 16 + lg * 4;
      const int cc = bn + wc * 64 + ni * 16 + lr;
      const float bv = bias[cc];
      const int hh = cc >> 6, dk = cc & 63;
      const int dh = dk >> 5, lgk = (dk & 31) >> 3, jq = dk & 7;
#pragma unroll
      for (int jj = 0; jj < 4; ++jj) {
        float v = acc[mi][ni][jj] + bv;
        int s = r0 + jj;
        if (z == 0) {
          size_t idx = ((((size_t)hh * 256 + (s >> 4)) * 2 + dh) * 64 + (s & 15) + 16 * lgk) * 8 + jq;
          outb[idx] = f2bf(v * 0.18033688011112042f);
        } else if (z == 1) {
          outf[((size_t)hh * M + s) * 64 + dk] = v;
          size_t idx = ((((size_t)hh * 256 + (s >> 4)) * 2 + dh) * 64 + (s & 15) + 16 * lgk) * 8 + jq;
          outb[idx] = f2bf(v);
        } else {
          outf[((size_t)hh * M + s) * 64 + dk] = v;
        }
      }
    }
  }
}

// ---------------- O-projection GEMM (fp32 row-major out) ----------------
__global__ __launch_bounds__(256)
void gemm_o(const ushort_t* __restrict__ A, const ushort_t* __restrict__ B,
            const float* __restrict__ bias, float* __restrict__ Cout)
{
  const int N = 1024, K = 1024;
  __shared__ __align__(16) ushort_t Al[128 * 32];
  __shared__ __align__(16) ushort_t Bl[128 * 32];
  const int tid = threadIdx.x;
  const int w = tid >> 6, l = tid & 63;
  const int lr = l & 15, lg = l >> 4;
  const int bm = blockIdx.x * 128, bn = blockIdx.y * 128;
  const int wr = w >> 1, wc = w & 1;
  f32x4 acc[4][4] = {};
  const int crow = l >> 2;
  const int ccol = (l & 3) * 8;

  for (int k0 = 0; k0 < K; k0 += 32) {
    __syncthreads();
#pragma unroll
    for (int i = 0; i < 2; ++i) {
      const int c = w * 2 + i;
      GLD16(A + (size_t)(bm + c * 16 + crow) * K + k0 + ccol, &Al[c * 512]);
      GLD16(B + (size_t)(bn + c * 16 + crow) * K + k0 + ccol, &Bl[c * 512]);
    }
    __syncthreads();
    bf16x8 af[4], bfr[4];
#pragma unroll
    for (int mi = 0; mi < 4; ++mi)
      af[mi] = *(const bf16x8*)&Al[(wr * 64 + mi * 16 + lr) * 32 + lg * 8];
#pragma unroll
    for (int ni = 0; ni < 4; ++ni)
      bfr[ni] = *(const bf16x8*)&Bl[(wc * 64 + ni * 16 + lr) * 32 + lg * 8];
#pragma unroll
    for (int mi = 0; mi < 4; ++mi)
#pragma unroll
      for (int ni = 0; ni < 4; ++ni)
        acc[mi][ni] = MFMA16(af[mi], bfr[ni], acc[mi][ni]);
  }

#pragma unroll
  for (int mi = 0; mi < 4; ++mi)
#pragma unroll
    for (int ni = 0; ni < 4; ++ni) {
      const int r0 = bm + wr * 64 + mi * 16 + lg * 4;
      const int cc = bn + wc * 64 + ni * 16 + lr;
      const float bv = bias[cc];
#pragma unroll
      for (int jj = 0; jj < 4; ++jj)
        Cout[(size_t)(r0 + jj) * N + cc] = acc[mi][ni][jj] + bv;
    }
}

// ---------------- pack V: head-major fp32 [16][S][64] -> tiled bf16 V^T ----------------
__global__ __launch_bounds__(256) void pack_vt(const float* __restrict__ Vhead,
                                               ushort_t* __restrict__ Vt) {
  const int S = 4096;
  int tile = blockIdx.x * 4 + (threadIdx.x >> 6);   // 8192 tiles
  int l = threadIdx.x & 63;
  int h = tile >> 9, rem = tile & 511;
  int kb = rem >> 2, dvt = rem & 3;
  int lr = l & 15, lg = l >> 4;
  const float* src = Vhead + ((size_t)h * S + kb * 32 + lg * 8) * 64 + dvt * 16 + lr;
  ushort8 o8;
#pragma unroll
  for (int j = 0; j < 8; ++j) o8[j] = f2bf(src[(size_t)j * 64]);
  *(ushort8*)&Vt[(size_t)tile * 512 + l * 8] = o8;
}

// ---------------- flash attention v3: LDS-staged K/V, counted-vmcnt pipeline ----------------
// Qt/Kt: tiled bf16 (Q pre-scaled by 0.125*log2e), Vt: tiled bf16 V^T, Ao: bf16 [S][1024]
// Grid: 512 flat blocks; flat = (h&7) + 8*((h>>3)*32 + xr), T = 31-xr  (XCD-aware: 2 heads/XCD)
__global__ __launch_bounds__(256, 2)
void attn(const ushort_t* __restrict__ Qt, const ushort_t* __restrict__ Kt,
          const ushort_t* __restrict__ Vt, ushort_t* __restrict__ Ao) {
  const int DM = 1024;
  const int flat = blockIdx.x;
  const int h = ((flat >> 8) << 3) + (flat & 7);   // (flat>>3)>>5 heads-hi, flat&7 lo
  const int xr = (flat >> 3) & 31;
  const int T = 31 - xr;                           // longest q-tiles first per XCD
  const int tid = threadIdx.x, w = tid >> 6, l = tid & 63;
  const int lr = l & 15, lg = l >> 4;
  const int qw = T * 128 + w * 32;                 // this wave's 32 q rows

  __shared__ __align__(16) ushort_t Kl[2][4096];   // 8KB per buf (64 keys x 64 dk)
  __shared__ __align__(16) ushort_t Vl[2][4096];
  __shared__ __align__(16) ushort_t plds[4][2048]; // per-wave P: 32 q x 64 keys
  char* pw = (char*)plds[w];
  const uint_t swz = (uint_t)(lr & 7) << 4;

  const ushort_t* Kbase = Kt + (size_t)h * 262144;
  const ushort_t* Vbase = Vt + (size_t)h * 262144;

  auto stage = [&](int t, int buf) {
    const ushort_t* ks = Kbase + (size_t)t * 4096;
    const ushort_t* vs = Vbase + (size_t)t * 4096;
#pragma unroll
    for (int r = 0; r < 2; ++r) {
      GLD16(ks + r * 2048 + w * 512 + l * 8, &Kl[buf][r * 2048 + w * 512]);
      GLD16(vs + r * 2048 + w * 512 + l * 8, &Vl[buf][r * 2048 + w * 512]);
    }
  };

  // Q fragments (B-operand of swapped QK): lane q = l&15
  const size_t hQ = (size_t)h * 256;
  bf16x8 qf[2][2];
#pragma unroll
  for (int qt = 0; qt < 2; ++qt)
#pragma unroll
    for (int dh = 0; dh < 2; ++dh)
      qf[qt][dh] = *(const bf16x8*)&Qt[(((hQ + (qw >> 4) + qt) * 2 + dh) << 9) + l * 8];

  f32x4 o[2][4] = {};          // [qt][dvt]; col(l&15)=q, row(lg*4+jj)=dv
  float m[2], lsum[2];
#pragma unroll
  for (int qt = 0; qt < 2; ++qt) { m[qt] = -__builtin_inff(); lsum[qt] = 0.0f; }

  const int ktm_step = (qw & ~63) >> 6;  // step at which masking starts (this wave)
  const int nt = 2 * T + 2;              // block-uniform step count

  stage(0, 0);
  for (int t = 0; t < nt; ++t) {
    const int buf = t & 1;
    if (t + 1 < nt) {
      stage(t + 1, buf ^ 1);
      asm volatile("s_waitcnt vmcnt(4)" ::: "memory");   // tile t landed (4 newer in flight)
    } else {
      asm volatile("s_waitcnt vmcnt(0)" ::: "memory");
    }
    __builtin_amdgcn_s_barrier();
    __builtin_amdgcn_sched_barrier(0);

    const int kt = t * 64;
    const bool domask = (t >= ktm_step);
    const ushort_t* Kb = Kl[buf];
    const ushort_t* Vb = Vl[buf];

    // ---- QK^T (swapped): st[kt4][qt]; lane: q=l&15, key=kt+kt4*16+lg*4+jj
    f32x4 st[4][2];
#pragma unroll
    for (int kt4 = 0; kt4 < 4; ++kt4) {
      bf16x8 k0 = *(const bf16x8*)&Kb[(kt4 * 2 + 0) * 512 + l * 8];
      bf16x8 k1 = *(const bf16x8*)&Kb[(kt4 * 2 + 1) * 512 + l * 8];
      f32x4 c0 = {}, c1 = {};
      c0 = MFMA16(k0, qf[0][0], c0);
      c0 = MFMA16(k1, qf[0][1], c0);
      c1 = MFMA16(k0, qf[1][0], c1);
      c1 = MFMA16(k1, qf[1][1], c1);
      st[kt4][0] = c0;
      st[kt4][1] = c1;
    }
    if (domask) {
#pragma unroll
      for (int kt4 = 0; kt4 < 4; ++kt4)
#pragma unroll
        for (int qt = 0; qt < 2; ++qt) {
          int qq = qw + qt * 16 + lr;
#pragma unroll
          for (int jj = 0; jj < 4; ++jj) {
            int key = kt + kt4 * 16 + lg * 4 + jj;
            if (key > qq) st[kt4][qt][jj] = -__builtin_inff();
          }
        }
    }
    // ---- online softmax (exp2 domain), defer-max rescale
#pragma unroll
    for (int qt = 0; qt < 2; ++qt) {
      float a0 = fmaxf(fmaxf(st[0][qt][0], st[0][qt][1]), fmaxf(st[0][qt][2], st[0][qt][3]));
      float a1 = fmaxf(fmaxf(st[1][qt][0], st[1][qt][1]), fmaxf(st[1][qt][2], st[1][qt][3]));
      float a2 = fmaxf(fmaxf(st[2][qt][0], st[2][qt][1]), fmaxf(st[2][qt][2], st[2][qt][3]));
      float a3 = fmaxf(fmaxf(st[3][qt][0], st[3][qt][1]), fmaxf(st[3][qt][2], st[3][qt][3]));
      float pm = fmaxf(fmaxf(a0, a1), fmaxf(a2, a3));
      pm = fmaxf(pm, __shfl_xor(pm, 16));
      pm = fmaxf(pm, __shfl_xor(pm, 32));
      float mn;
      if (__any(pm > m[qt] + 10.0f)) {      // wave-uniform: rescale path
        mn = fmaxf(m[qt], pm);
        float al = __builtin_amdgcn_exp2f(m[qt] - mn);
        m[qt] = mn;
        lsum[qt] *= al;
#pragma unroll
        for (int dvt = 0; dvt < 4; ++dvt)
#pragma unroll
          for (int jj = 0; jj < 4; ++jj) o[qt][dvt][jj] *= al;
      } else {
        mn = m[qt];                          // defer: P bounded by 2^10
      }
      float ps = 0.0f;
#pragma unroll
      for (int kt4 = 0; kt4 < 4; ++kt4) {
#pragma unroll
        for (int jj = 0; jj < 4; ++jj) {
          float e = __builtin_amdgcn_exp2f(st[kt4][qt][jj] - mn);
          st[kt4][qt][jj] = e;
          ps += e;
        }
      }
      ps += __shfl_xor(ps, 16);
      ps += __shfl_xor(ps, 32);
      lsum[qt] += ps;
      // write P rows to swizzled per-wave LDS (8B stores)
#pragma unroll
      for (int kt4 = 0; kt4 < 4; ++kt4) {
        ushort4 pk;
        pk.x = f2bfn(st[kt4][qt][0]); pk.y = f2bfn(st[kt4][qt][1]);
        pk.z = f2bfn(st[kt4][qt][2]); pk.w = f2bfn(st[kt4][qt][3]);
        uint_t bo = (uint_t)(qt * 16 + lr) * 128 + (uint_t)(kt4 * 32 + lg * 8);
        *(ushort4*)(pw + (bo ^ swz)) = pk;
      }
    }
    // ---- P fragments (B-operand of swapped PV)
    bf16x8 pa[2][2];
#pragma unroll
    for (int qt = 0; qt < 2; ++qt)
#pragma unroll
      for (int ks = 0; ks < 2; ++ks) {
        uint_t bo = (uint_t)(qt * 16 + lr) * 128 + (uint_t)(ks * 64 + lg * 16);
        pa[qt][ks] = *(const bf16x8*)(pw + (bo ^ swz));
      }
    // ---- PV (swapped): O[dv][q]
#pragma unroll
    for (int dvt = 0; dvt < 4; ++dvt)
#pragma unroll
      for (int ks = 0; ks < 2; ++ks) {
        bf16x8 vf = *(const bf16x8*)&Vb[(ks * 4 + dvt) * 512 + l * 8];
        o[0][dvt] = MFMA16(vf, pa[0][ks], o[0][dvt]);
        o[1][dvt] = MFMA16(vf, pa[1][ks], o[1][dvt]);
      }

    __builtin_amdgcn_sched_barrier(0);
    __builtin_amdgcn_s_barrier();          // protects buf^1 from next-iter stage
  }

  // ---- epilogue: divide by lsum (q = l&15), pack, store row-major
#pragma unroll
  for (int qt = 0; qt < 2; ++qt) {
    float inv = 1.0f / lsum[qt];
#pragma unroll
    for (int dvt = 0; dvt < 4; ++dvt) {
      ushort4 pk;
      pk.x = f2bfn(o[qt][dvt][0] * inv);
      pk.y = f2bfn(o[qt][dvt][1] * inv);
      pk.z = f2bfn(o[qt][dvt][2] * inv);
      pk.w = f2bfn(o[qt][dvt][3] * inv);
      *(ushort4*)&Ao[(size_t)(qw + qt * 16 + lr) * DM + h * 64 + dvt * 16 + lg * 4] = pk;
    }
  }
}

// ---------------- launch ----------------
extern "C" void kernel_launch(void* const* d_in, const int* in_sizes, int n_in,
                              void* d_out, int out_size, void* d_ws, size_t ws_size,
                              hipStream_t stream) {
  const int S = 4096, DM = 1024;
  const size_t NE = (size_t)S * DM;

  const float* q  = (const float*)d_in[0];
  const float* k  = (const float*)d_in[1];
  const float* v  = (const float*)d_in[2];
  const float* Wq = (const float*)d_in[3];
  const float* bq = (const float*)d_in[4];
  const float* Wk = (const float*)d_in[5];
  const float* bk = (const float*)d_in[6];
  const float* Wv = (const float*)d_in[7];
  const float* bv = (const float*)d_in[8];
  const float* Wo = (const float*)d_in[9];
  const float* bo = (const float*)d_in[10];

  // workspace (48 MB high-water, overlays on dead buffers)
  unsigned char* ws = (unsigned char*)d_ws;
  ushort_t* qb  = (ushort_t*)(ws);
  ushort_t* kb  = (ushort_t*)(ws + (8u << 20));
  ushort_t* vb  = (ushort_t*)(ws + (16u << 20));
  ushort_t* wqb = (ushort_t*)(ws + (24u << 20));
  ushort_t* wkb = (ushort_t*)(ws + (26u << 20));
  ushort_t* wvb = (ushort_t*)(ws + (28u << 20));
  ushort_t* wob = (ushort_t*)(ws + (30u << 20));
  ushort_t* qpb = (ushort_t*)(ws + (32u << 20));
  ushort_t* kpb = (ushort_t*)(ws + (40u << 20));
  ushort_t* vt  = kb;   // overlay: kb dead after qkv_gemm
  ushort_t* ao  = qb;   // overlay: qb dead after qkv_gemm

  float* outO = (float*)d_out;
  float* keyO = outO + NE;
  float* valO = keyO + NE;

  // 1) fused fp32->bf16 conversion (7 tensors)
  ConvArgs ca;
  ca.src[0] = q;  ca.src[1] = k;  ca.src[2] = v;
  ca.src[3] = Wq; ca.src[4] = Wk; ca.src[5] = Wv; ca.src[6] = Wo;
  ca.dst[0] = qb;  ca.dst[1] = kb;  ca.dst[2] = vb;
  ca.dst[3] = wqb; ca.dst[4] = wkb; ca.dst[5] = wvb; ca.dst[6] = wob;
  const int NB = 1048576, WB = 262144;
  ca.cum[0] = 0;
  ca.cum[1] = NB; ca.cum[2] = 2 * NB; ca.cum[3] = 3 * NB;
  ca.cum[4] = 3 * NB + WB; ca.cum[5] = 3 * NB + 2 * WB;
  ca.cum[6] = 3 * NB + 3 * WB; ca.cum[7] = 3 * NB + 4 * WB;
  convall<<<ca.cum[7] / 256, 256, 0, stream>>>(ca);

  // 2) fused QKV projections (Q/K write tiled bf16; K/V write fp32 head-major)
  QKVArgs qa;
  qa.A[0] = qb;  qa.A[1] = kb;  qa.A[2] = vb;
  qa.B[0] = wqb; qa.B[1] = wkb; qa.B[2] = wvb;
  qa.bias[0] = bq; qa.bias[1] = bk; qa.bias[2] = bv;
  qa.outf[0] = nullptr; qa.outf[1] = keyO; qa.outf[2] = valO;
  qa.outb[0] = qpb;     qa.outb[1] = kpb;  qa.outb[2] = nullptr;
  qkv_gemm<<<dim3(S / 128, DM / 128, 3), 256, 0, stream>>>(qa);

  // 3) pack V -> tiled bf16 V^T
  pack_vt<<<2048, 256, 0, stream>>>(valO, vt);

  // 4) flash attention (512 flat blocks, XCD-aware head mapping)
  attn<<<512, 256, 0, stream>>>(qpb, kpb, vt, ao);

  // 5) output projection
  gemm_o<<<dim3(S / 128, DM / 128), 256, 0, stream>>>(ao, wob, bo, outO);
}

// Round 7
// 266.709 us; speedup vs baseline: 2.6627x; 1.1485x over previous
//
#include <hip/hip_runtime.h>
#include <math.h>

typedef __attribute__((ext_vector_type(8))) __bf16 bf16x8;
typedef __attribute__((ext_vector_type(8))) unsigned short ushort8;
typedef __attribute__((ext_vector_type(4))) float f32x4;
typedef unsigned short ushort_t;
typedef unsigned int uint_t;

#define MFMA16(a,b,c) __builtin_amdgcn_mfma_f32_16x16x32_bf16(a,b,c,0,0,0)

#define GLD16(gp, lp) __builtin_amdgcn_global_load_lds( \
  (__attribute__((address_space(1))) const void*)(gp), \
  (__attribute__((address_space(3))) void*)(lp), 16, 0, 0)

__device__ __forceinline__ ushort_t f2bf(float f) {
  uint_t u = __builtin_bit_cast(uint_t, f);
  u = (u + 0x7fffu + ((u >> 16) & 1u)) >> 16;
  return (ushort_t)u;
}
// native cast (compiler emits v_cvt_pk_bf16_f32 for pairs)
__device__ __forceinline__ ushort_t f2bfn(float f) {
  __bf16 b = (__bf16)f;
  return __builtin_bit_cast(ushort_t, b);
}

// ---------------- fused fp32 -> bf16 convert (7 tensors, 1 launch) ----------------
struct ConvArgs {
  const float* src[7];
  ushort_t* dst[7];
  int cum[8];   // cumulative float4-counts
};

__global__ __launch_bounds__(256) void convall(ConvArgs a) {
  int flat = blockIdx.x * 256 + threadIdx.x;
  int s = 0;
#pragma unroll
  for (int i = 1; i < 7; ++i) if (flat >= a.cum[i]) s = i;
  int idx = flat - a.cum[s];
  float4 v = ((const float4*)a.src[s])[idx];
  ushort4 o;
  o.x = f2bf(v.x); o.y = f2bf(v.y); o.z = f2bf(v.z); o.w = f2bf(v.w);
  ((ushort4*)a.dst[s])[idx] = o;
}

// ---------------- fused QKV GEMM: C = A @ B^T + bias, z selects q/k/v ----------------
// Tiled fragment layout for attention (1KB tiles, MFMA lane order):
//   Q/K: idx = ((h*256 + s/16)*2 + dk/32)*512 + ((s&15) + 16*((dk&31)>>3))*8 + (dk&7)
struct QKVArgs {
  const ushort_t* A[3];
  const ushort_t* B[3];
  const float* bias[3];
  float* outf[3];
  ushort_t* outb[3];
};

__global__ __launch_bounds__(256)
void qkv_gemm(QKVArgs ar) {
  const int M = 4096, K = 1024;
  const int z = blockIdx.z;
  const ushort_t* __restrict__ A = ar.A[z];
  const ushort_t* __restrict__ B = ar.B[z];
  const float* __restrict__ bias = ar.bias[z];

  __shared__ __align__(16) ushort_t Al[128 * 32];
  __shared__ __align__(16) ushort_t Bl[128 * 32];
  const int tid = threadIdx.x;
  const int w = tid >> 6, l = tid & 63;
  const int lr = l & 15, lg = l >> 4;
  const int bm = blockIdx.x * 128, bn = blockIdx.y * 128;
  const int wr = w >> 1, wc = w & 1;
  f32x4 acc[4][4] = {};

  const int crow = l >> 2;
  const int ccol = (l & 3) * 8;

  for (int k0 = 0; k0 < K; k0 += 32) {
    __syncthreads();
#pragma unroll
    for (int i = 0; i < 2; ++i) {
      const int c = w * 2 + i;
      GLD16(A + (size_t)(bm + c * 16 + crow) * K + k0 + ccol, &Al[c * 512]);
      GLD16(B + (size_t)(bn + c * 16 + crow) * K + k0 + ccol, &Bl[c * 512]);
    }
    __syncthreads();
    bf16x8 af[4], bfr[4];
#pragma unroll
    for (int mi = 0; mi < 4; ++mi)
      af[mi] = *(const bf16x8*)&Al[(wr * 64 + mi * 16 + lr) * 32 + lg * 8];
#pragma unroll
    for (int ni = 0; ni < 4; ++ni)
      bfr[ni] = *(const bf16x8*)&Bl[(wc * 64 + ni * 16 + lr) * 32 + lg * 8];
#pragma unroll
    for (int mi = 0; mi < 4; ++mi)
#pragma unroll
      for (int ni = 0; ni < 4; ++ni)
        acc[mi][ni] = MFMA16(af[mi], bfr[ni], acc[mi][ni]);
  }

  float* outf = ar.outf[z];
  ushort_t* outb = ar.outb[z];
#pragma unroll
  for (int mi = 0; mi < 4; ++mi) {
#pragma unroll
    for (int ni = 0; ni < 4; ++ni) {
      const int r0 = bm + wr * 64 + mi * 16 + lg * 4;
      const int cc = bn + wc * 64 + ni * 16 + lr;
      const float bv = bias[cc];
      const int hh = cc >> 6, dk = cc & 63;
      const int dh = dk >> 5, lgk = (dk & 31) >> 3, jq = dk & 7;
#pragma unroll
      for (int jj = 0; jj < 4; ++jj) {
        float v = acc[mi][ni][jj] + bv;
        int s = r0 + jj;
        if (z == 0) {
          size_t idx = ((((size_t)hh * 256 + (s >> 4)) * 2 + dh) * 64 + (s & 15) + 16 * lgk) * 8 + jq;
          outb[idx] = f2bf(v * 0.18033688011112042f);
        } else if (z == 1) {
          outf[((size_t)hh * M + s) * 64 + dk] = v;
          size_t idx = ((((size_t)hh * 256 + (s >> 4)) * 2 + dh) * 64 + (s & 15) + 16 * lgk) * 8 + jq;
          outb[idx] = f2bf(v);
        } else {
          outf[((size_t)hh * M + s) * 64 + dk] = v;
        }
      }
    }
  }
}

// ---------------- O-projection GEMM (fp32 row-major out) ----------------
__global__ __launch_bounds__(256)
void gemm_o(const ushort_t* __restrict__ A, const ushort_t* __restrict__ B,
            const float* __restrict__ bias, float* __restrict__ Cout)
{
  const int N = 1024, K = 1024;
  __shared__ __align__(16) ushort_t Al[128 * 32];
  __shared__ __align__(16) ushort_t Bl[128 * 32];
  const int tid = threadIdx.x;
  const int w = tid >> 6, l = tid & 63;
  const int lr = l & 15, lg = l >> 4;
  const int bm = blockIdx.x * 128, bn = blockIdx.y * 128;
  const int wr = w >> 1, wc = w & 1;
  f32x4 acc[4][4] = {};
  const int crow = l >> 2;
  const int ccol = (l & 3) * 8;

  for (int k0 = 0; k0 < K; k0 += 32) {
    __syncthreads();
#pragma unroll
    for (int i = 0; i < 2; ++i) {
      const int c = w * 2 + i;
      GLD16(A + (size_t)(bm + c * 16 + crow) * K + k0 + ccol, &Al[c * 512]);
      GLD16(B + (size_t)(bn + c * 16 + crow) * K + k0 + ccol, &Bl[c * 512]);
    }
    __syncthreads();
    bf16x8 af[4], bfr[4];
#pragma unroll
    for (int mi = 0; mi < 4; ++mi)
      af[mi] = *(const bf16x8*)&Al[(wr * 64 + mi * 16 + lr) * 32 + lg * 8];
#pragma unroll
    for (int ni = 0; ni < 4; ++ni)
      bfr[ni] = *(const bf16x8*)&Bl[(wc * 64 + ni * 16 + lr) * 32 + lg * 8];
#pragma unroll
    for (int mi = 0; mi < 4; ++mi)
#pragma unroll
      for (int ni = 0; ni < 4; ++ni)
        acc[mi][ni] = MFMA16(af[mi], bfr[ni], acc[mi][ni]);
  }

#pragma unroll
  for (int mi = 0; mi < 4; ++mi)
#pragma unroll
    for (int ni = 0; ni < 4; ++ni) {
      const int r0 = bm + wr * 64 + mi * 16 + lg * 4;
      const int cc = bn + wc * 64 + ni * 16 + lr;
      const float bv = bias[cc];
#pragma unroll
      for (int jj = 0; jj < 4; ++jj)
        Cout[(size_t)(r0 + jj) * N + cc] = acc[mi][ni][jj] + bv;
    }
}

// ---------------- pack V: head-major fp32 [16][S][64] -> tiled bf16 V^T ----------------
__global__ __launch_bounds__(256) void pack_vt(const float* __restrict__ Vhead,
                                               ushort_t* __restrict__ Vt) {
  const int S = 4096;
  int tile = blockIdx.x * 4 + (threadIdx.x >> 6);   // 8192 tiles
  int l = threadIdx.x & 63;
  int h = tile >> 9, rem = tile & 511;
  int kb = rem >> 2, dvt = rem & 3;
  int lr = l & 15, lg = l >> 4;
  const float* src = Vhead + ((size_t)h * S + kb * 32 + lg * 8) * 64 + dvt * 16 + lr;
  ushort8 o8;
#pragma unroll
  for (int j = 0; j < 8; ++j) o8[j] = f2bf(src[(size_t)j * 64]);
  *(ushort8*)&Vt[(size_t)tile * 512 + l * 8] = o8;
}

// ---------------- flash attention v4: 16 q/wave, exact tile-pairing, register K/V ----
// Qt/Kt: tiled bf16 (Q pre-scaled by 0.125*log2e), Vt: tiled bf16 V^T, Ao: bf16 [S][1024]
// 512 blocks x 256 thr; per head 256 16-row q-tiles; wave handles tiles {t, 255-t}
// -> uniform 65-66 steps per wave (causal balance). Heads pinned 2/XCD.
__global__ __launch_bounds__(256)
void attn(const ushort_t* __restrict__ Qt, const ushort_t* __restrict__ Kt,
          const ushort_t* __restrict__ Vt, ushort_t* __restrict__ Ao) {
  const int DM = 1024;
  const int flat = blockIdx.x;
  const int xcd = flat & 7, i = flat >> 3;          // i: 0..63
  const int h = xcd * 2 + (i & 1);
  const int b = i >> 1;                              // 0..31 per head
  const int tid = threadIdx.x, w = tid >> 6, l = tid & 63;
  const int lr = l & 15, lg = l >> 4;
  const int t_lo = b * 4 + w;                        // 0..127

  // per-wave P buffer: 16 q x 64 keys bf16 (2KB), XOR-swizzled
  __shared__ __align__(16) ushort_t plds[4][1024];
  char* pw = (char*)plds[w];
  const uint_t swz = (uint_t)(lr & 7) << 4;

  const size_t hQ = (size_t)h * 256;
  const ushort_t* __restrict__ Vh = Vt + (size_t)h * 262144;

#pragma unroll 1
  for (int seg = 0; seg < 2; ++seg) {
    const int t = seg ? (255 - t_lo) : t_lo;
    const int qw = t * 16;

    // Q fragments (B-operand of swapped QK): lane q = l&15
    bf16x8 qf[2];
#pragma unroll
    for (int dh = 0; dh < 2; ++dh)
      qf[dh] = *(const bf16x8*)&Qt[(((hQ + t) * 2 + dh) << 9) + l * 8];

    f32x4 o[4] = {};            // [dvt]; col(l&15)=q, row(lg*4+jj)=dv
    float m = -__builtin_inff(), lsum = 0.0f;

    bf16x8 kc[8], kn[8], vf[8];
    auto loadK8 = [&](bf16x8* dst, int kt) {
#pragma unroll
      for (int kt4 = 0; kt4 < 4; ++kt4)
#pragma unroll
        for (int dh = 0; dh < 2; ++dh)
          dst[kt4 * 2 + dh] =
              *(const bf16x8*)&Kt[(((hQ + (kt >> 4) + kt4) * 2 + dh) << 9) + l * 8];
    };

    const int ktm = qw & ~63;        // last (masked) step
    loadK8(kc, 0);
    for (int kt = 0; kt <= ktm; kt += 64) {
      // early-issue V for this step
#pragma unroll
      for (int ks = 0; ks < 2; ++ks)
#pragma unroll
        for (int dvt = 0; dvt < 4; ++dvt)
          vf[ks * 4 + dvt] =
              *(const bf16x8*)&Vh[(((size_t)(kt >> 5) + ks) * 4 + dvt) << 9 | (l * 8)];
      const bool last = (kt == ktm);
      if (!last) loadK8(kn, kt + 64);  // cross-step K prefetch

      // ---- QK^T (swapped): st[kt4]; lane: q=l&15, key=kt+kt4*16+lg*4+jj
      f32x4 st[4];
#pragma unroll
      for (int kt4 = 0; kt4 < 4; ++kt4) {
        f32x4 c = {};
        c = MFMA16(kc[kt4 * 2 + 0], qf[0], c);
        c = MFMA16(kc[kt4 * 2 + 1], qf[1], c);
        st[kt4] = c;
      }
      if (last) {
        int qq = qw + lr;
#pragma unroll
        for (int kt4 = 0; kt4 < 4; ++kt4)
#pragma unroll
          for (int jj = 0; jj < 4; ++jj) {
            int key = kt + kt4 * 16 + lg * 4 + jj;
            if (key > qq) st[kt4][jj] = -__builtin_inff();
          }
      }
      // ---- online softmax (exp2 domain), defer-max rescale
      float a0 = fmaxf(fmaxf(st[0][0], st[0][1]), fmaxf(st[0][2], st[0][3]));
      float a1 = fmaxf(fmaxf(st[1][0], st[1][1]), fmaxf(st[1][2], st[1][3]));
      float a2 = fmaxf(fmaxf(st[2][0], st[2][1]), fmaxf(st[2][2], st[2][3]));
      float a3 = fmaxf(fmaxf(st[3][0], st[3][1]), fmaxf(st[3][2], st[3][3]));
      float pm = fmaxf(fmaxf(a0, a1), fmaxf(a2, a3));
      pm = fmaxf(pm, __shfl_xor(pm, 16));
      pm = fmaxf(pm, __shfl_xor(pm, 32));
      if (__any(pm > m + 10.0f)) {       // wave-uniform rescale path
        float mn = fmaxf(m, pm);
        float al = __builtin_amdgcn_exp2f(m - mn);
        m = mn;
        lsum *= al;
#pragma unroll
        for (int dvt = 0; dvt < 4; ++dvt)
#pragma unroll
          for (int jj = 0; jj < 4; ++jj) o[dvt][jj] *= al;
      }
      float ps = 0.0f;
#pragma unroll
      for (int kt4 = 0; kt4 < 4; ++kt4)
#pragma unroll
        for (int jj = 0; jj < 4; ++jj) {
          float e = __builtin_amdgcn_exp2f(st[kt4][jj] - m);
          st[kt4][jj] = e;
          ps += e;
        }
      ps += __shfl_xor(ps, 16);
      ps += __shfl_xor(ps, 32);
      lsum += ps;
      // ---- P rows to swizzled per-wave LDS (8B stores), reread as B-fragments
#pragma unroll
      for (int kt4 = 0; kt4 < 4; ++kt4) {
        ushort4 pk;
        pk.x = f2bfn(st[kt4][0]); pk.y = f2bfn(st[kt4][1]);
        pk.z = f2bfn(st[kt4][2]); pk.w = f2bfn(st[kt4][3]);
        uint_t bo = (uint_t)lr * 128 + (uint_t)(kt4 * 32 + lg * 8);
        *(ushort4*)(pw + (bo ^ swz)) = pk;
      }
      bf16x8 pa[2];
#pragma unroll
      for (int ks = 0; ks < 2; ++ks) {
        uint_t bo = (uint_t)lr * 128 + (uint_t)(ks * 64 + lg * 16);
        pa[ks] = *(const bf16x8*)(pw + (bo ^ swz));
      }
      // ---- PV (swapped): O[dv][q]
#pragma unroll
      for (int dvt = 0; dvt < 4; ++dvt)
#pragma unroll
        for (int ks = 0; ks < 2; ++ks)
          o[dvt] = MFMA16(vf[ks * 4 + dvt], pa[ks], o[dvt]);

      if (!last) {
#pragma unroll
        for (int r = 0; r < 8; ++r) kc[r] = kn[r];
      }
    }

    // ---- epilogue: divide by lsum (q = l&15), pack, store row-major
    float inv = 1.0f / lsum;
#pragma unroll
    for (int dvt = 0; dvt < 4; ++dvt) {
      ushort4 pk;
      pk.x = f2bfn(o[dvt][0] * inv);
      pk.y = f2bfn(o[dvt][1] * inv);
      pk.z = f2bfn(o[dvt][2] * inv);
      pk.w = f2bfn(o[dvt][3] * inv);
      *(ushort4*)&Ao[(size_t)(qw + lr) * DM + h * 64 + dvt * 16 + lg * 4] = pk;
    }
  }
}

// ---------------- launch ----------------
extern "C" void kernel_launch(void* const* d_in, const int* in_sizes, int n_in,
                              void* d_out, int out_size, void* d_ws, size_t ws_size,
                              hipStream_t stream) {
  const int S = 4096, DM = 1024;
  const size_t NE = (size_t)S * DM;

  const float* q  = (const float*)d_in[0];
  const float* k  = (const float*)d_in[1];
  const float* v  = (const float*)d_in[2];
  const float* Wq = (const float*)d_in[3];
  const float* bq = (const float*)d_in[4];
  const float* Wk = (const float*)d_in[5];
  const float* bk = (const float*)d_in[6];
  const float* Wv = (const float*)d_in[7];
  const float* bv = (const float*)d_in[8];
  const float* Wo = (const float*)d_in[9];
  const float* bo = (const float*)d_in[10];

  // workspace (48 MB high-water, overlays on dead buffers)
  unsigned char* ws = (unsigned char*)d_ws;
  ushort_t* qb  = (ushort_t*)(ws);
  ushort_t* kb  = (ushort_t*)(ws + (8u << 20));
  ushort_t* vb  = (ushort_t*)(ws + (16u << 20));
  ushort_t* wqb = (ushort_t*)(ws + (24u << 20));
  ushort_t* wkb = (ushort_t*)(ws + (26u << 20));
  ushort_t* wvb = (ushort_t*)(ws + (28u << 20));
  ushort_t* wob = (ushort_t*)(ws + (30u << 20));
  ushort_t* qpb = (ushort_t*)(ws + (32u << 20));
  ushort_t* kpb = (ushort_t*)(ws + (40u << 20));
  ushort_t* vt  = kb;   // overlay: kb dead after qkv_gemm
  ushort_t* ao  = qb;   // overlay: qb dead after qkv_gemm

  float* outO = (float*)d_out;
  float* keyO = outO + NE;
  float* valO = keyO + NE;

  // 1) fused fp32->bf16 conversion (7 tensors)
  ConvArgs ca;
  ca.src[0] = q;  ca.src[1] = k;  ca.src[2] = v;
  ca.src[3] = Wq; ca.src[4] = Wk; ca.src[5] = Wv; ca.src[6] = Wo;
  ca.dst[0] = qb;  ca.dst[1] = kb;  ca.dst[2] = vb;
  ca.dst[3] = wqb; ca.dst[4] = wkb; ca.dst[5] = wvb; ca.dst[6] = wob;
  const int NB = 1048576, WB = 262144;
  ca.cum[0] = 0;
  ca.cum[1] = NB; ca.cum[2] = 2 * NB; ca.cum[3] = 3 * NB;
  ca.cum[4] = 3 * NB + WB; ca.cum[5] = 3 * NB + 2 * WB;
  ca.cum[6] = 3 * NB + 3 * WB; ca.cum[7] = 3 * NB + 4 * WB;
  convall<<<ca.cum[7] / 256, 256, 0, stream>>>(ca);

  // 2) fused QKV projections (Q/K write tiled bf16; K/V write fp32 head-major)
  QKVArgs qa;
  qa.A[0] = qb;  qa.A[1] = kb;  qa.A[2] = vb;
  qa.B[0] = wqb; qa.B[1] = wkb; qa.B[2] = wvb;
  qa.bias[0] = bq; qa.bias[1] = bk; qa.bias[2] = bv;
  qa.outf[0] = nullptr; qa.outf[1] = keyO; qa.outf[2] = valO;
  qa.outb[0] = qpb;     qa.outb[1] = kpb;  qa.outb[2] = nullptr;
  qkv_gemm<<<dim3(S / 128, DM / 128, 3), 256, 0, stream>>>(qa);

  // 3) pack V -> tiled bf16 V^T
  pack_vt<<<2048, 256, 0, stream>>>(valO, vt);

  // 4) flash attention (512 blocks, exact pairing, 2 heads/XCD)
  attn<<<512, 256, 0, stream>>>(qpb, kpb, vt, ao);

  // 5) output projection
  gemm_o<<<dim3(S / 128, DM / 128), 256, 0, stream>>>(ao, wob, bo, outO);
}